// Round 5
// baseline (20.036 us; speedup 1.0000x reference)
//
#include <hip/hip_runtime.h>

typedef unsigned long long u64;
typedef float v4f __attribute__((ext_vector_type(4)));
typedef unsigned int v4u __attribute__((ext_vector_type(4)));

// Exact integer re-implementation of the reference "spiking" fp64-multiplier
// circuit. Bit convention: array index j (0..63) of a row == bit (63-j) of
// the packed uint64 (sign at array[0] == bit 63).
__device__ __forceinline__ u64 fp64mul_circuit(u64 a, u64 b) {
    const u64 FRACM = 0xFFFFFFFFFFFFFULL; // low 52 bits
    u64 sA = a >> 63, sB = b >> 63;
    unsigned eA = (unsigned)((a >> 52) & 0x7FF);
    unsigned eB = (unsigned)((b >> 52) & 0x7FF);
    u64 mA = a & FRACM, mB = b & FRACM;
    u64 sign = sA ^ sB;

    u64 MA = mA | ((u64)(eA != 0) << 52);
    u64 MB = mB | ((u64)(eB != 0) << 52);
    __uint128_t P = (__uint128_t)MA * (__uint128_t)MB; // < 2^106, in 108-bit field

    u64 hi = (u64)(P >> 64), lo = (u64)P;
    int lzc;
    if (hi)      lzc = __clzll(hi) - 20;      // bits 107..64 live in hi[43:0]
    else if (lo) lzc = 44 + __clzll(lo);
    else         lzc = 108;

    __uint128_t norm = P << lzc;              // leading one -> bit 107 (P==0 -> 0)

    u64 mant53     = (u64)(norm >> 55);                  // bits 107..55
    unsigned guard = (unsigned)(((u64)(norm >> 54)) & 1);
    unsigned lsb   = (unsigned)(mant53 & 1);
    unsigned sticky = ((norm & ((((__uint128_t)1) << 54) - 1)) != 0) ? 1u : 0u;
    unsigned rnd   = guard & (sticky | lsb);             // round to nearest even

    u64 sum = mant53 + (u64)rnd;
    unsigned rcarry = (unsigned)((sum >> 53) & 1);
    u64 frac52 = sum & FRACM;

    int Emod = ((int)eA + (int)eB + 3 - 1023 - lzc + (int)rcarry) & 8191;
    int neg    = (Emod >> 12) & 1;
    int e_zero = (Emod == 0) ? 1 : 0;
    int underflow = neg | e_zero;
    int overflow  = (neg ^ 1) & ((((Emod >> 11) & 1) | ((Emod & 0x7FF) == 0x7FF)) ? 1 : 0);
    u64 exp11 = (u64)(Emod & 0x7FF);

    bool a_ones = (eA == 0x7FF), b_ones = (eB == 0x7FF);
    bool a_mnz = (mA != 0), b_mnz = (mB != 0);
    bool A_nan = a_ones && a_mnz,  B_nan = b_ones && b_mnz;
    bool A_inf = a_ones && !a_mnz, B_inf = b_ones && !b_mnz;
    bool A_zero = (eA == 0) && !a_mnz, B_zero = (eB == 0) && !b_mnz;

    bool nan_sel  = A_nan || B_nan || (A_inf && B_zero) || (B_inf && A_zero);
    bool inf_sel  = A_inf || B_inf || (overflow != 0);
    bool zero_sel = A_zero || B_zero || (underflow != 0);

    u64 expo = exp11, fraco = frac52;
    if (zero_sel) { expo = 0;     fraco = 0; }
    if (inf_sel)  { expo = 0x7FF; fraco = 0; }
    if (nan_sel)  { expo = 0x7FF; fraco = 1ULL << 51; } // qnan: frac MSB only

    return (sign << 63) | (expo << 52) | fraco;
}

#define ROWS 8    // rows per wave (finer blocks -> better channel balance)
#define WPB  4    // waves per block (256 threads)

// Streaming kernel: nontemporal dwordx4 loads/stores (read-once/write-once
// data should not pollute L2/L3), wave-private LDS transpose in the middle.
__global__ __launch_bounds__(256) void spike_fp64_mul_kernel(
    const float* __restrict__ A, const float* __restrict__ B,
    float* __restrict__ out, int n)
{
    __shared__ alignas(16) unsigned char nibA[WPB][ROWS][16];
    __shared__ alignas(16) unsigned char nibB[WPB][ROWS][16];
    __shared__ u64 resLds[WPB][ROWS];

    int lane = threadIdx.x & 63;
    int wib  = threadIdx.x >> 6;
    int wave = (blockIdx.x * blockDim.x + threadIdx.x) >> 6;
    int k = lane >> 4;   // row sub-index within a 4-row load instruction
    int m = lane & 15;   // float4 (nibble) slot within a row

    size_t rowbase = (size_t)wave * ROWS;
    const v4f* A4 = reinterpret_cast<const v4f*>(A);
    const v4f* B4 = reinterpret_cast<const v4f*>(B);

    // Front-load all 4 x 1KB nontemporal loads.
    v4f ra[2], rb[2];
    #pragma unroll
    for (int j = 0; j < 2; ++j)
        ra[j] = __builtin_nontemporal_load(&A4[(rowbase + 4 * j + k) * 16 + m]);
    #pragma unroll
    for (int j = 0; j < 2; ++j)
        rb[j] = __builtin_nontemporal_load(&B4[(rowbase + 4 * j + k) * 16 + m]);

    // Each float4 becomes a nibble (bit c = col 4m+c of its row).
    #pragma unroll
    for (int j = 0; j < 2; ++j) {
        int row = 4 * j + k;
        unsigned na = (unsigned)(ra[j][0] > 0.5f)       | ((unsigned)(ra[j][1] > 0.5f) << 1)
                    | ((unsigned)(ra[j][2] > 0.5f) << 2) | ((unsigned)(ra[j][3] > 0.5f) << 3);
        unsigned nb = (unsigned)(rb[j][0] > 0.5f)       | ((unsigned)(rb[j][1] > 0.5f) << 1)
                    | ((unsigned)(rb[j][2] > 0.5f) << 2) | ((unsigned)(rb[j][3] > 0.5f) << 3);
        nibA[wib][row][m] = (unsigned char)na;
        nibB[wib][row][m] = (unsigned char)nb;
    }
    __syncthreads();

    // Lane reconstructs row (lane&7) as packed u64 (bit idx = col); lanes
    // 8..63 duplicate (LDS broadcast, no divergence). b128 reads: 8 distinct
    // 16B rows span all 32 banks -> conflict-free.
    int rr = lane & 7;
    v4u wa = *reinterpret_cast<const v4u*>(nibA[wib][rr]);
    v4u wb = *reinterpret_cast<const v4u*>(nibB[wib][rr]);
    u64 rowA = 0, rowB = 0;
    #pragma unroll
    for (int q = 0; q < 4; ++q) {
        unsigned v = wa[q] & 0x0F0F0F0Fu;           // byte t holds nibble 4q+t
        v = (v | (v >> 4)) & 0x00FF00FFu;
        v = (v | (v >> 8)) & 0x0000FFFFu;           // 16 bits: bit 4t+c
        rowA |= (u64)v << (16 * q);
        unsigned w = wb[q] & 0x0F0F0F0Fu;
        w = (w | (w >> 4)) & 0x00FF00FFu;
        w = (w | (w >> 8)) & 0x0000FFFFu;
        rowB |= (u64)w << (16 * q);
    }

    // Circuit wants MSB-first packing (bit 63-idx).
    u64 res = fp64mul_circuit(__brevll(rowA), __brevll(rowB));

    if (lane < ROWS) resLds[wib][lane] = res;
    __syncthreads();

    // 2 x 1KB nontemporal stores: inst i covers rows 4i..4i+3.
    #pragma unroll
    for (int i = 0; i < 2; ++i) {
        int row = 4 * i + k;
        u64 v = resLds[wib][row];                   // 16-lane broadcast reads
        unsigned nib = (unsigned)(v >> (60 - 4 * m)) & 0xFu; // cols 4m..4m+3
        v4f o;
        o[0] = (float)((nib >> 3) & 1);
        o[1] = (float)((nib >> 2) & 1);
        o[2] = (float)((nib >> 1) & 1);
        o[3] = (float)(nib & 1);
        __builtin_nontemporal_store(o, reinterpret_cast<v4f*>(out) + (rowbase + row) * 16 + m);
    }
}

extern "C" void kernel_launch(void* const* d_in, const int* in_sizes, int n_in,
                              void* d_out, int out_size, void* d_ws, size_t ws_size,
                              hipStream_t stream) {
    const float* A = (const float*)d_in[0];
    const float* B = (const float*)d_in[1];
    float* out = (float*)d_out;
    int n = in_sizes[0] / 64;            // rows (131072; multiple of 32)
    int block = 256;                     // 4 waves x 8 rows = 32 rows/block
    int grid = n / (WPB * ROWS);
    spike_fp64_mul_kernel<<<grid, block, 0, stream>>>(A, B, out, n);
}